// Round 4
// baseline (920.238 us; speedup 1.0000x reference)
//
#include <hip/hip_runtime.h>
#include <stdint.h>

typedef __attribute__((ext_vector_type(8))) short short8;
typedef __attribute__((ext_vector_type(4))) float floatx4;

__device__ __forceinline__ unsigned short f2bf(float f) {
    unsigned u = __float_as_uint(f);
    u += 0x7FFFu + ((u >> 16) & 1u);
    return (unsigned short)(u >> 16);
}

__device__ __forceinline__ void gload_lds16(const void* g, void* l) {
    __builtin_amdgcn_global_load_lds(
        (const __attribute__((address_space(1))) unsigned int*)g,
        (__attribute__((address_space(3))) unsigned int*)l, 16, 0, 0);
}

// ---- prep: X fp32 -> bf16 (same layout) ----
__global__ __launch_bounds__(256)
void conv_x(const float* __restrict__ x, unsigned short* __restrict__ xb) {
    const size_t total = (size_t)16384 * 1024;
    for (size_t i = ((size_t)blockIdx.x * 256 + threadIdx.x) * 8; i < total;
         i += (size_t)2048 * 256 * 8) {
        float4 a = *(const float4*)&x[i];
        float4 b = *(const float4*)&x[i + 4];
        uint4 o;
        o.x = f2bf(a.x) | ((unsigned)f2bf(a.y) << 16);
        o.y = f2bf(a.z) | ((unsigned)f2bf(a.w) << 16);
        o.z = f2bf(b.x) | ((unsigned)f2bf(b.y) << 16);
        o.w = f2bf(b.z) | ((unsigned)f2bf(b.w) << 16);
        *(uint4*)&xb[i] = o;
    }
}

// ---- prep: W [1024][N] fp32 -> Wt [N][1024] bf16 (LDS-tiled transpose) ----
__global__ __launch_bounds__(256)
void transpose_w(const float* __restrict__ src, unsigned short* __restrict__ dst, int N) {
    __shared__ float T[64][65];
    const int t = threadIdx.x;
    const int k0 = blockIdx.x * 64, n0 = blockIdx.y * 64;
    const int r = t >> 4, c4 = (t & 15) * 4;
#pragma unroll
    for (int i = 0; i < 4; i++) {
        float4 v = *(const float4*)&src[(size_t)(k0 + r + 16 * i) * N + n0 + c4];
        T[r + 16 * i][c4] = v.x; T[r + 16 * i][c4 + 1] = v.y;
        T[r + 16 * i][c4 + 2] = v.z; T[r + 16 * i][c4 + 3] = v.w;
    }
    __syncthreads();
#pragma unroll
    for (int i = 0; i < 4; i++) {
        const int n = n0 + r + 16 * i;
        unsigned short b0 = f2bf(T[c4 + 0][r + 16 * i]);
        unsigned short b1 = f2bf(T[c4 + 1][r + 16 * i]);
        unsigned short b2 = f2bf(T[c4 + 2][r + 16 * i]);
        unsigned short b3 = f2bf(T[c4 + 3][r + 16 * i]);
        uint2 pv;
        pv.x = b0 | ((unsigned)b1 << 16);
        pv.y = b2 | ((unsigned)b3 << 16);
        *(uint2*)&dst[(size_t)n * 1024 + k0 + c4] = pv;
    }
}

__global__ __launch_bounds__(128)
void pack_bias(const float* __restrict__ bq, const float* __restrict__ bk,
               float* __restrict__ bqk) {
    const int t = threadIdx.x;
    bqk[t] = (t < 64) ? bq[t] : bk[t - 64];
}

// ---- m97-style 128x128 bf16 GEMM: C = A[M][1024] @ Bt[N][1024]^T + bias ----
template<bool TRS>
__global__ __launch_bounds__(256)
void gemm_bf16(const unsigned short* __restrict__ A,
               const unsigned short* __restrict__ Bt,
               const float* __restrict__ bias,
               unsigned short* __restrict__ out, int M, int N)
{
    __shared__ unsigned short As[128 * 32];
    __shared__ unsigned short Bs[128 * 32];
    const int tid = threadIdx.x;
    const int w = tid >> 6, l = tid & 63;
    const int quad = l >> 4, l16 = l & 15;
    const int wr = w >> 1, wc = w & 1;
    const int m0 = blockIdx.x * 128, n0 = blockIdx.y * 128;

    const int lr = l >> 2, lk = (l & 3) * 8;
    const unsigned short* Ag0 = A + (size_t)(m0 + w * 16 + lr) * 1024 + lk;
    const unsigned short* Ag1 = Ag0 + (size_t)64 * 1024;
    const unsigned short* Bg0 = Bt + (size_t)(n0 + w * 16 + lr) * 1024 + lk;
    const unsigned short* Bg1 = Bg0 + (size_t)64 * 1024;
    unsigned short* Al0 = &As[w * 512 + l * 8];
    unsigned short* Bl0 = &Bs[w * 512 + l * 8];

    floatx4 acc[4][4];
#pragma unroll
    for (int i = 0; i < 4; i++)
#pragma unroll
        for (int j = 0; j < 4; j++) acc[i][j] = (floatx4)0.f;

    for (int e0 = 0; e0 < 1024; e0 += 32) {
        gload_lds16(Ag0 + e0, Al0);
        gload_lds16(Ag1 + e0, Al0 + 2048);
        gload_lds16(Bg0 + e0, Bl0);
        gload_lds16(Bg1 + e0, Bl0 + 2048);
        __syncthreads();
        short8 af[4], bf[4];
#pragma unroll
        for (int i = 0; i < 4; i++)
            af[i] = *(const short8*)&As[(wr * 64 + i * 16 + l16) * 32 + quad * 8];
#pragma unroll
        for (int j = 0; j < 4; j++)
            bf[j] = *(const short8*)&Bs[(wc * 64 + j * 16 + l16) * 32 + quad * 8];
#pragma unroll
        for (int i = 0; i < 4; i++)
#pragma unroll
            for (int j = 0; j < 4; j++)
                acc[i][j] = __builtin_amdgcn_mfma_f32_16x16x32_bf16(af[i], bf[j], acc[i][j], 0, 0, 0);
        __syncthreads();
    }

#pragma unroll
    for (int j = 0; j < 4; j++) {
        const int n = n0 + wc * 64 + j * 16 + l16;
        const float bn = bias[n];
#pragma unroll
        for (int i = 0; i < 4; i++) {
            const int mb = m0 + wr * 64 + i * 16 + quad * 4;
            if (TRS) {
                unsigned short t[4];
#pragma unroll
                for (int r = 0; r < 4; r++) t[r] = f2bf(acc[i][j][r] + bn);
                uint2 pv;
                pv.x = t[0] | ((unsigned)t[1] << 16);
                pv.y = t[2] | ((unsigned)t[3] << 16);
                *(uint2*)&out[(size_t)n * M + mb] = pv;
            } else {
#pragma unroll
                for (int r = 0; r < 4; r++)
                    out[(size_t)(mb + r) * N + n] = f2bf(acc[i][j][r] + bn);
            }
        }
    }
}

// ---- attention v4: barrier-free, LDS-free; S^T trick + ds_bpermute exchange ----
// Block = 4 waves (one per 16-q-row group), dv slice = 128 cols.
// Grid = (qt 64, heavy first) x (b 4) x (dvf 8) = 2048 blocks x 256 threads.
__global__ __launch_bounds__(256, 3)
void attn_fused(const unsigned short* __restrict__ QKb, // 16384 x 128 bf16 (Q|K)
                const unsigned short* __restrict__ Vt,  // 1024 x 16384 bf16 (dv, bs)
                const float* __restrict__ maskx,        // 4 x 4096
                float* __restrict__ out)                // 4 x 4096 x 1024
{
    const int tid = threadIdx.x;
    const int rb = tid >> 6;                 // wave = q-row block 0..3
    const int lane = tid & 63;
    const int quad = lane >> 4, l16 = lane & 15;
    const int bid = blockIdx.x;
    const int combo = bid & 31;              // low bits -> XCD spread
    const int b = combo & 3;
    const int dvf = combo >> 2;              // 0..7
    const int qt = 63 - (bid >> 5);          // heavy tiles first (backfill balance)
    const int q0 = qt * 64;
    const int qrow = q0 + rb * 16 + l16;     // this lane's q row (S^T phase)
    const int dv0 = dvf * 128;

    // Q fragment (B-operand of S^T): Q[q=l16][k=quad*8+j], k in [0,64)
    const unsigned short* qbase = QKb + (size_t)(b * 4096 + qrow) * 128;
    const short8 qa0 = *(const short8*)(qbase + quad * 8);
    const short8 qa1 = *(const short8*)(qbase + 32 + quad * 8);

    const bool pq = maskx[b * 4096 + qrow] < -1e30f;

    floatx4 acc[8];
#pragma unroll
    for (int i = 0; i < 8; i++) acc[i] = (floatx4)0.f;
    float lacc = 0.f;

    const int niter = 2 * qt + 2;
    // per-lane bases
    const unsigned short* vbase = Vt + (size_t)(dv0 + l16) * 16384 + b * 4096 + quad * 8;
    const unsigned short* kbase = QKb + (size_t)(b * 4096 + l16) * 128 + 64 + quad * 8;
    const float* mbase = maskx + b * 4096 + quad * 4;

    const int idx0 = (((quad & 1) * 2 + 0) * 16 + l16) * 4;  // bpermute byte indices
    const int idx1 = (((quad & 1) * 2 + 1) * 16 + l16) * 4;
    const bool hi = quad >= 2;

    for (int kt = 0; kt < niter; kt++) {
        const int k0 = kt * 32;
        // V loads first (consumed last)
        short8 vb[8];
#pragma unroll
        for (int cb = 0; cb < 8; cb++)
            vb[cb] = *(const short8*)(vbase + (size_t)cb * (16 * 16384) + k0);
        // K fragments for the two 16-key tiles
        const unsigned short* kp0 = kbase + (size_t)k0 * 128;
        const unsigned short* kp1 = kbase + (size_t)(k0 + 16) * 128;
        const short8 ka0lo = *(const short8*)kp0;
        const short8 ka0hi = *(const short8*)(kp0 + 32);
        const short8 ka1lo = *(const short8*)kp1;
        const short8 ka1hi = *(const short8*)(kp1 + 32);
        // mask values for this lane's 8 keys
        const float4 mk0 = *(const float4*)(mbase + k0);
        const float4 mk1 = *(const float4*)(mbase + k0 + 16);
        // S^T tiles: D[key_local=quad*4+r][q=l16]
        floatx4 s0 = (floatx4)0.f, s1 = (floatx4)0.f;
        s0 = __builtin_amdgcn_mfma_f32_16x16x32_bf16(ka0lo, qa0, s0, 0, 0, 0);
        s0 = __builtin_amdgcn_mfma_f32_16x16x32_bf16(ka0hi, qa1, s0, 0, 0, 0);
        s1 = __builtin_amdgcn_mfma_f32_16x16x32_bf16(ka1lo, qa0, s1, 0, 0, 0);
        s1 = __builtin_amdgcn_mfma_f32_16x16x32_bf16(ka1hi, qa1, s1, 0, 0, 0);
        // exp + mask
        const float* m0a = (const float*)&mk0;
        const float* m1a = (const float*)&mk1;
        float p0[4], p1[4];
#pragma unroll
        for (int r = 0; r < 4; r++) {
            const int key0 = k0 + quad * 4 + r;
            const int key1 = key0 + 16;
            const bool ok0 = (key0 <= qrow) && ((m0a[r] < -1e30f) == pq);
            const bool ok1 = (key1 <= qrow) && ((m1a[r] < -1e30f) == pq);
            p0[r] = ok0 ? __expf(s0[r] * 0.125f) : 0.f;
            p1[r] = ok1 ? __expf(s1[r] * 0.125f) : 0.f;
            lacc += p0[r] + p1[r];
        }
        // pack to bf16 pairs (C-layout regs)
        const int t0pk0 = (int)(f2bf(p0[0]) | ((unsigned)f2bf(p0[1]) << 16));
        const int t0pk1 = (int)(f2bf(p0[2]) | ((unsigned)f2bf(p0[3]) << 16));
        const int t1pk0 = (int)(f2bf(p1[0]) | ((unsigned)f2bf(p1[1]) << 16));
        const int t1pk1 = (int)(f2bf(p1[2]) | ((unsigned)f2bf(p1[3]) << 16));
        // intra-wave C-layout -> A-layout exchange
        union { int i[4]; short8 s8; } pf;
        {
            const int a0 = __builtin_amdgcn_ds_bpermute(idx0, t0pk0);
            const int b0 = __builtin_amdgcn_ds_bpermute(idx0, t1pk0);
            pf.i[0] = hi ? b0 : a0;
            const int a1 = __builtin_amdgcn_ds_bpermute(idx0, t0pk1);
            const int b1 = __builtin_amdgcn_ds_bpermute(idx0, t1pk1);
            pf.i[1] = hi ? b1 : a1;
            const int a2 = __builtin_amdgcn_ds_bpermute(idx1, t0pk0);
            const int b2 = __builtin_amdgcn_ds_bpermute(idx1, t1pk0);
            pf.i[2] = hi ? b2 : a2;
            const int a3 = __builtin_amdgcn_ds_bpermute(idx1, t0pk1);
            const int b3 = __builtin_amdgcn_ds_bpermute(idx1, t1pk1);
            pf.i[3] = hi ? b3 : a3;
        }
        // PV: acc[cb] += P(16x32) @ V^T slice
#pragma unroll
        for (int cb = 0; cb < 8; cb++)
            acc[cb] = __builtin_amdgcn_mfma_f32_16x16x32_bf16(pf.s8, vb[cb], acc[cb], 0, 0, 0);
    }

    // row-sum totals: sum across the 4 quads holding the same l16
    lacc += __shfl_xor(lacc, 16);
    lacc += __shfl_xor(lacc, 32);
    // redistribute: lane needs l for q rows quad*4+r (held at lane quad*4+r)
    float inv[4];
#pragma unroll
    for (int r = 0; r < 4; r++)
        inv[r] = 1.f / __shfl(lacc, quad * 4 + r);

#pragma unroll
    for (int r = 0; r < 4; r++) {
        const int orow = b * 4096 + q0 + rb * 16 + quad * 4 + r;
#pragma unroll
        for (int cb = 0; cb < 8; cb++)
            out[(size_t)orow * 1024 + dv0 + cb * 16 + l16] = acc[cb][r] * inv[r];
    }
}

extern "C" void kernel_launch(void* const* d_in, const int* in_sizes, int n_in,
                              void* d_out, int out_size, void* d_ws, size_t ws_size,
                              hipStream_t stream) {
    const float* x  = (const float*)d_in[0];
    const float* Wq = (const float*)d_in[1];
    const float* bq = (const float*)d_in[2];
    const float* Wk = (const float*)d_in[3];
    const float* bk = (const float*)d_in[4];
    const float* Wv = (const float*)d_in[5];
    const float* bv = (const float*)d_in[6];
    const float* mk = (const float*)d_in[7];
    float* out = (float*)d_out;

    const int M = 4 * 4096;  // 16384
    char* ws = (char*)d_ws;
    unsigned short* Xb   = (unsigned short*)ws;                      // 32 MB
    unsigned short* Vt   = (unsigned short*)(ws + (33554432));       // 32 MB (1024 x 16384)
    unsigned short* Wvt  = (unsigned short*)(ws + (67108864));       // 2 MB  (1024 x 1024)
    unsigned short* Wqkt = (unsigned short*)(ws + (69206016));       // 256 KB (128 x 1024)
    unsigned short* QKb  = (unsigned short*)(ws + (69468160));       // 4 MB  (16384 x 128)
    float*          bqk  = (float*)(ws + (73662464));                // 512 B

    conv_x<<<2048, 256, 0, stream>>>(x, Xb);
    transpose_w<<<dim3(16, 16), 256, 0, stream>>>(Wv, Wvt, 1024);
    transpose_w<<<dim3(16, 1), 256, 0, stream>>>(Wq, Wqkt, 64);
    transpose_w<<<dim3(16, 1), 256, 0, stream>>>(Wk, Wqkt + 64 * 1024, 64);
    pack_bias<<<1, 128, 0, stream>>>(bq, bk, bqk);

    gemm_bf16<true ><<<dim3(128, 8), 256, 0, stream>>>(Xb, Wvt, bv, Vt, M, 1024);
    gemm_bf16<false><<<dim3(128, 1), 256, 0, stream>>>(Xb, Wqkt, bqk, QKb, M, 128);

    attn_fused<<<dim3(2048), 256, 0, stream>>>(QKb, Vt, mk, out);
}